// Round 23
// baseline (123.748 us; speedup 1.0000x reference)
//
#include <hip/hip_runtime.h>
#include <hip/hip_bf16.h>
#include <math.h>

// B=2, S=2048, D=1024, H=16, dk=64.
// wsplit4 (all W -> fp16) -> fused tri-GEMM (A fp32 reg-staged at DISTANCE 2 ->
// fp16 LDS tile, 1-term fp16 MFMA, fused RoPE / tiled-V epilogues, counted-vmcnt
// TWO-barrier pipeline, 32KB LDS) -> 32x32-MFMA flash attention (counted-vmcnt,
// fp16 hi/lo X epilogue) -> fp16 2-term GEMM0.
//
// trigemm dist-2 queue (per thread, issue order): steady state at data-ready
// fence = [W(t), A(t+1)x2, W(t+1), A(t+2)x2] -> vmcnt(5) retires exactly W(t);
// compiler's wait before cvtpk(A(t+1)) leaves [W(t+1), A(t+2)x2] in flight.
// A(t+1) issued a FULL iteration earlier -> HBM latency covered. Tail:
// t=30 vmcnt(3), t=31 vmcnt(0). Two barriers/iter (r21 lesson: the middle
// barrier creates the wave-slip overlap window).
//
// trigemm LDS/buf (16KB x2 = 32KB): A f16 8KB | W f16 8KB, both [128][32]
//  swz(R,c) superrow-XOR layout. A written by reg-staging ds_write_b128;
//  W by 1 gload_lds/thread (linear dest = tid*16, source inverse-permuted).
// gemm0 LDS/buf (24KB x2): Xh 8K | Xl 8K | W 8K.
// Tiled K per (b,h): tile t at t*4096; elem(key r, dk d) = chunk(d>>3)*512+r*8+(d&7).
// Tiled V per (b,h): tile t at t*4096; elem(dk d, key s) = chunk((s&63)>>3)*512+d*8+(s&7).
//
// ws (64 MB): [0,8) Xh [8,16) Xl | [16,24) qb | [24,32) vt | [40,48) kb |
//  [48,64) W fp16: Wq @0, Wk @1M, Wv @2M, Wo @3M shorts.

#define B_ 2
#define S_ 2048
#define D_ 1024
#define H_ 16
#define DK 64

typedef __attribute__((ext_vector_type(8)))  __bf16    bf16x8;
typedef __attribute__((ext_vector_type(8)))  _Float16  f16x8;
typedef __attribute__((ext_vector_type(4)))  float     f32x4;
typedef __attribute__((ext_vector_type(16))) float     f32x16;
typedef __attribute__((ext_vector_type(8)))  unsigned short u16x8;
typedef __attribute__((ext_vector_type(4)))  unsigned short u16x4;

#if __has_builtin(__builtin_amdgcn_exp2f)
#define EXP2(x) __builtin_amdgcn_exp2f(x)
#else
#define EXP2(x) exp2f(x)
#endif

static __device__ __forceinline__ unsigned short f2bf(float x) {
    union { float f; unsigned u; } v; v.f = x;
    unsigned r = v.u + 0x7FFFu + ((v.u >> 16) & 1u);   // RNE
    return (unsigned short)(r >> 16);
}
static __device__ __forceinline__ unsigned cvtpk(float lo, float hi) {
    unsigned r;
    asm("v_cvt_pk_bf16_f32 %0, %1, %2" : "=v"(r) : "v"(lo), "v"(hi));
    return r;
}
static __device__ __forceinline__ unsigned cvtpk16(float lo, float hi) {
    unsigned r;
    asm("v_cvt_pkrtz_f16_f32 %0, %1, %2" : "=v"(r) : "v"(lo), "v"(hi));
    return r;
}
static __device__ __forceinline__ void gload_lds16(const void* g, void* l) {
    __builtin_amdgcn_global_load_lds(
        (const __attribute__((address_space(1))) void*)g,
        (__attribute__((address_space(3))) void*)l, 16, 0, 0);
}
static __device__ __forceinline__ int swz(int R, int c) {
    return ((R >> 1) << 6) + (((((R & 1) << 2) | c) ^ ((R >> 1) & 7)) << 3);
}
// fp16 hi/lo split of 2 fp32 (RTZ pack; lo corrects remainder).
static __device__ __forceinline__ void splitpk16(float e0, float e1,
                                                 unsigned& hd, unsigned& ld) {
    hd = cvtpk16(e0, e1);
    union { unsigned u; _Float16 h[2]; } t; t.u = hd;
    ld = cvtpk16(e0 - (float)t.h[0], e1 - (float)t.h[1]);
}

// ---------------------------------------------------------------------------
// All 4 weights fp32 -> fp16 (RNE). out: weight t at t*1M shorts.
// ---------------------------------------------------------------------------
__global__ __launch_bounds__(256) void wsplit4(
    const float* __restrict__ W0, const float* __restrict__ W1,
    const float* __restrict__ W2, const float* __restrict__ W3,
    unsigned short* __restrict__ out)
{
    const int idx = blockIdx.x * 256 + threadIdx.x;
    const int t = idx >> 17;
    const size_t e = (size_t)(idx & 131071) * 8;
    const float* src = (t==0 ? W0 : t==1 ? W1 : t==2 ? W2 : W3) + e;
    float4 a = *(const float4*)src;
    float4 b = *(const float4*)(src + 4);
    float x[8] = {a.x,a.y,a.z,a.w,b.x,b.y,b.z,b.w};
    union { _Float16 h[8]; u16x8 v; } Hh;
    #pragma unroll
    for (int j = 0; j < 8; ++j) Hh.h[j] = (_Float16)x[j];   // RNE
    *(u16x8*)(out + (size_t)t * 1048576 + e) = Hh.v;
}

// ---------------------------------------------------------------------------
// Fused tri-GEMM, 1-term fp16 MFMA, A reg-staged dist-2, two-barrier pipeline.
// ---------------------------------------------------------------------------
__global__ __launch_bounds__(512) void trigemm(
    const float* __restrict__ Aq, const float* __restrict__ Ak,
    const float* __restrict__ Av, const unsigned short* __restrict__ wsp,
    const float* __restrict__ bq, const float* __restrict__ bk,
    const float* __restrict__ bv,
    unsigned short* __restrict__ qb, unsigned short* __restrict__ kb,
    unsigned short* __restrict__ vt)
{
    __shared__ __align__(16) char ldsb[32768];   // 2 bufs x (A16 8K | W 8K)
    const int pid = blockIdx.z;
    const float* A    = (pid==0) ? Aq : (pid==1) ? Ak : Av;
    const float* bias = (pid==0) ? bq : (pid==1) ? bk : bv;
    const unsigned short* Whp = wsp + (size_t)pid * 1048576;

    const int tid = threadIdx.x;
    const int w = tid >> 6, lane = tid & 63;
    const int l15 = lane & 15, g4 = lane >> 4;
    const int wr = w >> 1, wc = w & 1;
    const int bx = blockIdx.x, by = blockIdx.y;

    // A reg-staging: thread -> row tid>>2, 8-fp32 chunk tid&3
    const int arow = tid >> 2, ac = tid & 3;
    const float* gpA = A + (size_t)(bx*128 + arow) * 1024 + ac * 8;
    const int aoff = swz(arow, ac);          // shorts offset in A16 tile

    // W staging: 1 gload_lds/thread; dest unit = tid (linear), source inverse-swz
    const int sr_ = tid >> 3, slot_ = tid & 7;
    const int z_  = slot_ ^ (sr_ & 7);
    const int wR_ = sr_*2 + (z_ >> 2);
    const unsigned short* gpW = Whp + (size_t)(by*128 + wR_) * 1024 + (z_ & 3) * 8;

    f32x4 acc[2][4];
    #pragma unroll
    for (int m = 0; m < 2; ++m)
        #pragma unroll
        for (int n = 0; n < 4; ++n) acc[m][n] = (f32x4){0.f,0.f,0.f,0.f};

    float4 pa0, pa1, pb0, pb1;   // two named A-reg sets (parity-static)

    // ---- prologue: tile 0 staged; A(1) left in flight ----
    {
        float4 p0 = *(const float4*)(gpA);
        float4 p1 = *(const float4*)(gpA + 4);
        gload_lds16(gpW, ldsb + 8192 + tid * 16);          // W(0) -> buf0
        union { unsigned u[4]; u16x8 v; } hh;              // (compiler waits A(0))
        hh.u[0] = cvtpk16(p0.x, p0.y); hh.u[1] = cvtpk16(p0.z, p0.w);
        hh.u[2] = cvtpk16(p1.x, p1.y); hh.u[3] = cvtpk16(p1.z, p1.w);
        *(u16x8*)((unsigned short*)ldsb + aoff) = hh.v;
        pa0 = *(const float4*)(gpA + 32);                  // A(1) -> regs
        pa1 = *(const float4*)(gpA + 36);
        asm volatile("s_waitcnt vmcnt(2) lgkmcnt(0)" ::: "memory"); // W(0) retired
        __builtin_amdgcn_s_barrier();
        asm volatile("" ::: "memory");
    }

    // body: ca = A(t+1) regs (loaded at t-1); cb receives A(t+2)
    auto body = [&](int t, float4& ca0, float4& ca1, float4& cb0, float4& cb1) {
        const int cur = t & 1;
        if (t < 31)
            gload_lds16(gpW + (size_t)(t+1)*32,
                        ldsb + (cur^1)*16384 + 8192 + tid*16);   // W(t+1)
        if (t < 30) {
            cb0 = *(const float4*)(gpA + (size_t)(t+2)*32);      // A(t+2)
            cb1 = *(const float4*)(gpA + (size_t)(t+2)*32 + 4);
        }
        if (t < 30)      asm volatile("s_waitcnt vmcnt(5)" ::: "memory"); // W(t) retired
        else if (t < 31) asm volatile("s_waitcnt vmcnt(3)" ::: "memory");
        else             asm volatile("s_waitcnt vmcnt(0)" ::: "memory");
        __builtin_amdgcn_s_barrier();                            // tile-t data-ready
        asm volatile("" ::: "memory");

        const unsigned short* Ab = (const unsigned short*)(ldsb + cur*16384);
        const unsigned short* Wb = Ab + 4096;
        f16x8 ah[2], wh4[4];
        #pragma unroll
        for (int m = 0; m < 2; ++m)
            ah[m] = *(const f16x8*)(Ab + swz(wr*32 + m*16 + l15, g4));
        #pragma unroll
        for (int n = 0; n < 4; ++n)
            wh4[n] = *(const f16x8*)(Wb + swz(wc*64 + n*16 + l15, g4));
        #pragma unroll
        for (int m = 0; m < 2; ++m)
            #pragma unroll
            for (int n = 0; n < 4; ++n)
                acc[m][n] = __builtin_amdgcn_mfma_f32_16x16x32_f16(ah[m], wh4[n], acc[m][n], 0,0,0);

        if (t < 31) {   // convert + write A(t+1) (loaded a full iter ago)
            union { unsigned u[4]; u16x8 v; } hh;
            hh.u[0] = cvtpk16(ca0.x, ca0.y); hh.u[1] = cvtpk16(ca0.z, ca0.w);
            hh.u[2] = cvtpk16(ca1.x, ca1.y); hh.u[3] = cvtpk16(ca1.z, ca1.w);
            *(u16x8*)((unsigned short*)(ldsb + (cur^1)*16384) + aoff) = hh.v;
        }
        asm volatile("s_waitcnt lgkmcnt(0)" ::: "memory");       // A-write visible
        __builtin_amdgcn_s_barrier();                            // read-done
        asm volatile("" ::: "memory");
    };
    for (int t2 = 0; t2 < 32; t2 += 2) {
        body(t2,     pa0, pa1, pb0, pb1);
        body(t2 + 1, pb0, pb1, pa0, pa1);
    }

    const int colBase = by*128 + wc*64;
    const int rowBase = bx*128 + wr*32;
    const int h = colBase >> 6;

    if (pid < 2) {
        unsigned short* Out = pid ? kb : qb;
        const float QSC = pid ? 1.0f : 0.125f * 1.44269504088896340736f;
        #pragma unroll
        for (int m = 0; m < 2; ++m) {
            const int srow0 = rowBase + m*16 + g4*4;
            const int b = srow0 >> 11;
            unsigned short* hb2 = Out + (size_t)(b*H_ + h) * S_ * DK;
            #pragma unroll
            for (int n = 0; n < 2; ++n) {
                const int d = n*16 + l15;
                const float invf = exp2f((float)d * -0.4152410118609203f);
                const float b1 = bias[h*64 + d], b2 = bias[h*64 + d + 32];
                #pragma unroll
                for (int r = 0; r < 4; ++r) {
                    const int s = (srow0 + r) & 2047;
                    const float x1 = acc[m][n][r]   + b1;
                    const float x2 = acc[m][n+2][r] + b2;
                    float sn, cc;
                    __sincosf((float)s * invf, &sn, &cc);
                    const float o1 = (x1*cc - x2*sn) * QSC;
                    const float o2 = (x2*cc + x1*sn) * QSC;
                    if (pid == 0) {
                        unsigned short* dst = hb2 + (size_t)s * DK;
                        dst[d]      = f2bf(o1);
                        dst[d + 32] = f2bf(o2);
                    } else {
                        unsigned short* tb = hb2 + (s >> 6) * 4096 + (s & 63) * 8;
                        tb[(d >> 3) * 512 + (d & 7)]        = f2bf(o1);
                        tb[(d >> 3) * 512 + 2048 + (d & 7)] = f2bf(o2);
                    }
                }
            }
        }
    } else {
        #pragma unroll
        for (int m = 0; m < 2; ++m) {
            const int srow0 = rowBase + m*16 + g4*4;
            const int b = srow0 >> 11, s0 = srow0 & 2047;
            unsigned short* tb = vt + (size_t)(b*H_ + h) * S_ * DK
                               + (s0 >> 6) * 4096 + ((s0 & 63) >> 3) * 512 + (s0 & 7);
            #pragma unroll
            for (int n = 0; n < 4; ++n) {
                const int d = n*16 + l15;
                const float bb = bias[h*64 + d];
                u16x4 pk;
                #pragma unroll
                for (int r = 0; r < 4; ++r) pk[r] = f2bf(acc[m][n][r] + bb);
                *(u16x4*)(tb + d * 8) = pk;
            }
        }
    }
}

// ---------------------------------------------------------------------------
// Output projection: fp16 2-term (Xh*W + Xl*W), counted-vmcnt two-barrier.
// ---------------------------------------------------------------------------
__global__ __launch_bounds__(512) void mfma_gemm0(
    const unsigned short* __restrict__ Ah, const unsigned short* __restrict__ Al,
    const unsigned short* __restrict__ Wh,
    const float* __restrict__ bias, float* __restrict__ Out)
{
    __shared__ __align__(16) char ldsb[49152];   // 2 bufs x (Xh 8K | Xl 8K | W 8K)
    const int tid = threadIdx.x;
    const int w = tid >> 6, lane = tid & 63;
    const int l15 = lane & 15, g4 = lane >> 4;
    const int wr = w >> 1, wc = w & 1;
    const int bx = blockIdx.x, by = blockIdx.y;

    const int u_ = w >> 1, qq = w & 1;
    const unsigned short* gsrc = (u_==0) ? Ah : (u_==1) ? Al : Wh;
    const int row0 = (u_ < 2) ? bx * 128 : by * 128;
    const int lr8 = lane >> 3;
    const int zz  = (lane & 7) ^ lr8;
    const int wR0 = qq*64 + (lr8 << 1) + (zz >> 2);
    const unsigned short* gp0 = gsrc + (size_t)(row0 + wR0) * 1024 + (zz & 3) * 8;

    f32x4 acc[2][4];
    #pragma unroll
    for (int m = 0; m < 2; ++m)
        #pragma unroll
        for (int n = 0; n < 4; ++n) acc[m][n] = (f32x4){0.f,0.f,0.f,0.f};

    #define STAGE(T, BUF) do {                                              \
        if (w < 6) {                                                        \
            const unsigned short* g_ = gp0 + (size_t)(T) * 32;              \
            char* d_ = ldsb + (BUF)*24576 + u_*8192 + qq*4096;              \
            gload_lds16(g_,          d_);                                   \
            gload_lds16(g_ + 16384,  d_ + 1024);                            \
            gload_lds16(g_ + 32768,  d_ + 2048);                            \
            gload_lds16(g_ + 49152,  d_ + 3072);                            \
        }                                                                   \
    } while (0)

    STAGE(0, 0);
    asm volatile("s_waitcnt vmcnt(0)" ::: "memory");
    __builtin_amdgcn_s_barrier();
    asm volatile("" ::: "memory");

    for (int t = 0; t < 32; ++t) {
        const int cur = t & 1;
        if (t < 31) {
            STAGE(t + 1, cur ^ 1);
            asm volatile("s_waitcnt vmcnt(4)" ::: "memory");
        } else {
            asm volatile("s_waitcnt vmcnt(0)" ::: "memory");
        }
        __builtin_amdgcn_s_barrier();
        asm volatile("" ::: "memory");

        const unsigned short* Ahb = (const unsigned short*)(ldsb + cur*24576);
        const unsigned short* Alb = Ahb + 4096;
        const unsigned short* Whb = Ahb + 8192;

        f16x8 ah2[2], al2[2], wh4[4];
        #pragma unroll
        for (int m = 0; m < 2; ++m) {
            const int off = swz(wr*32 + m*16 + l15, g4);
            ah2[m] = *(const f16x8*)(Ahb + off);
            al2[m] = *(const f16x8*)(Alb + off);
        }
        #pragma unroll
        for (int n = 0; n < 4; ++n) {
            const int off = swz(wc*64 + n*16 + l15, g4);
            wh4[n] = *(const f16x8*)(Whb + off);
        }
        #pragma unroll
        for (int m = 0; m < 2; ++m)
            #pragma unroll
            for (int n = 0; n < 4; ++n) {
                acc[m][n] = __builtin_amdgcn_mfma_f32_16x16x32_f16(ah2[m], wh4[n], acc[m][n], 0,0,0);
                acc[m][n] = __builtin_amdgcn_mfma_f32_16x16x32_f16(al2[m], wh4[n], acc[m][n], 0,0,0);
            }

        asm volatile("" ::: "memory");
        __builtin_amdgcn_s_barrier();
        asm volatile("" ::: "memory");
    }
    #undef STAGE

    const int colBase = by*128 + wc*64;
    const int rowBase = bx*128 + wr*32;
    #pragma unroll
    for (int m = 0; m < 2; ++m) {
        const int row = rowBase + m*16 + g4*4;
        #pragma unroll
        for (int n = 0; n < 4; ++n) {
            const int col = colBase + n*16 + l15;
            const float bb = bias[col];
            #pragma unroll
            for (int r = 0; r < 4; ++r)
                Out[(size_t)(row + r) * 1024 + col] = acc[m][n][r] + bb;
        }
    }
}

// ---------------------------------------------------------------------------
// 32x32-MFMA flash attention, counted-vmcnt two-barrier; fp16 hi/lo X epilogue.
// ---------------------------------------------------------------------------
__global__ __launch_bounds__(512, 1) void attn_mfma8(
    const unsigned short* __restrict__ Qb, const unsigned short* __restrict__ Kb,
    const unsigned short* __restrict__ Vt,
    unsigned short* __restrict__ Xh, unsigned short* __restrict__ Xl)
{
    __shared__ __align__(16) char lds[65536];
    const unsigned bid = blockIdx.x;
    const int xcd = bid & 7, idx = bid >> 3;
    const int bh  = xcd * 4 + (idx >> 3);
    const int qt  = idx & 7;
    const int tid = threadIdx.x;
    const int w = tid >> 6, lane = tid & 63;
    const int l31 = lane & 31, hi = lane >> 5;
    const size_t bhO = (size_t)bh * S_ * DK;
    const int q0 = qt * 256 + w * 32;

    const int u0   = w * 4;
    const int isV  = u0 >> 4;
    const int u15  = u0 & 15;
    const int su0  = u15 >> 3;
    const unsigned short* sb = (isV ? Vt : Kb) + bhO;
    const int ch0 = u15 & 7;
    char* const dbase = lds;

    bf16x8 qf[4];
    #pragma unroll
    for (int ks = 0; ks < 4; ++ks)
        qf[ks] = *(const bf16x8*)(Qb + bhO + (size_t)(q0 + l31) * DK + ks*16 + hi*8);

    f32x16 oT[2];
    #pragma unroll
    for (int dh = 0; dh < 2; ++dh)
        #pragma unroll
        for (int r = 0; r < 16; ++r) oT[dh][r] = 0.f;
    float l_ = 0.f;

    #define ASTAGE(T, BUF) do {                                                     \
        const unsigned short* g_ = sb + (size_t)((T)*2 + su0) * 4096 + ch0 * 512    \
                                   + lane * 8;                                      \
        char* d_ = dbase + (BUF)*32768 + isV*16384 + su0*8192 + ch0*1024 + lane*16; \
        gload_lds16(g_,         d_);                                                \
        gload_lds16(g_ + 512,   d_ + 1024);                                         \
        gload_lds16(g_ + 1024,  d_ + 2048);                                         \
        gload_lds16(g_ + 1536,  d_ + 3072);                                         \
    } while (0)

    ASTAGE(0, 0);
    asm volatile("s_waitcnt vmcnt(0)" ::: "memory");
    __builtin_amdgcn_s_barrier();
    asm volatile("" ::: "memory");

    for (int t = 0; t < 16; ++t) {
        const int cur = t & 1;
        if (t < 15) {
            ASTAGE(t + 1, cur ^ 1);
            asm volatile("s_waitcnt vmcnt(4)" ::: "memory");
        } else {
            asm volatile("s_waitcnt vmcnt(0)" ::: "memory");
        }
        __builtin_amdgcn_s_barrier();
        asm volatile("" ::: "memory");

        const char* Kl = lds + cur * 32768;
        const char* Vl = Kl + 16384;

        f32x16 s2[4];
        __builtin_amdgcn_s_setprio(1);
        #pragma unroll
        for (int kb2 = 0; kb2 < 4; ++kb2) {
            f32x16 a;
            #pragma unroll
            for (int r = 0; r < 16; ++r) a[r] = 0.f;
            const char* kbase = Kl + (kb2 >> 1) * 8192 + ((kb2 & 1) * 32 + l31) * 16;
            #pragma unroll
            for (int ks = 0; ks < 4; ++ks) {
                bf16x8 kf = *(const bf16x8*)(kbase + (ks*2 + hi) * 1024);
                a = __builtin_amdgcn_mfma_f32_32x32x16_bf16(kf, qf[ks], a, 0, 0, 0);
            }
            s2[kb2] = a;
        }
        __builtin_amdgcn_s_setprio(0);

        {
            float lsum = 0.f;
            #pragma unroll
            for (int kb2 = 0; kb2 < 4; ++kb2)
                #pragma unroll
                for (int r = 0; r < 16; ++r) {
                    const float p = EXP2(s2[kb2][r]);
                    s2[kb2][r] = p; lsum += p;
                }
            l_ += lsum;
        }

        #pragma unroll
        for (int ks2 = 0; ks2 < 8; ++ks2) {
            const int kb2 = ks2 >> 1;
            const int R0  = (ks2 & 1) * 8;
            unsigned a0 = cvtpk(s2[kb2][R0+0], s2[kb2][R0+1]);
            unsigned a1 = cvtpk(s2[kb2][R0+2], s2[kb2][R0+3]);
            unsigned b0 = cvtpk(s2[kb2][R0+4], s2[kb2][R0+5]);
            unsigned b1 = cvtpk(s2[kb2][R0+6], s2[kb2][R0+7]);
            asm("v_permlane32_swap_b32 %0, %1" : "+v"(a0), "+v"(b0));
            asm("v_permlane32_swap_b32 %0, %1" : "+v"(a1), "+v"(b1));
            union { unsigned u[4]; bf16x8 v; } pf;
            pf.u[0] = a0; pf.u[1] = a1; pf.u[2] = b0; pf.u[3] = b1;
            const char* vbase = Vl + (ks2 >> 2) * 8192 + (((ks2 & 3) * 2) + hi) * 1024;
            __builtin_amdgcn_s_setprio(1);
            #pragma unroll
            for (int dh = 0; dh < 2; ++dh) {
                bf16x8 vf = *(const bf16x8*)(vbase + (dh*32 + l31) * 16);
                oT[dh] = __builtin_amdgcn_mfma_f32_32x32x16_bf16(vf, pf.v, oT[dh], 0, 0, 0);
            }
            __builtin_amdgcn_s_setprio(0);
        }

        asm volatile("" ::: "memory");
        __builtin_amdgcn_s_barrier();
        asm volatile("" ::: "memory");
    }
    #undef ASTAGE

    l_ += __shfl_xor(l_, 32, 64);
    const float inv = 1.0f / l_;
    const int b = bh >> 4, h = bh & 15;
    const int q = q0 + l31;
    unsigned short* xh = Xh + (((size_t)b * S_ + q) * H_ + h) * DK;
    unsigned short* xl = Xl + (((size_t)b * S_ + q) * H_ + h) * DK;
    #pragma unroll
    for (int dh = 0; dh < 2; ++dh)
        #pragma unroll
        for (int tt = 0; tt < 4; ++tt) {
            const int dk0 = dh*32 + tt*8 + hi*4;
            const float o0 = oT[dh][tt*4 + 0] * inv;
            const float o1 = oT[dh][tt*4 + 1] * inv;
            const float o2 = oT[dh][tt*4 + 2] * inv;
            const float o3 = oT[dh][tt*4 + 3] * inv;
            union { unsigned u[2]; u16x4 v; } hv, lv;
            splitpk16(o0, o1, hv.u[0], lv.u[0]);
            splitpk16(o2, o3, hv.u[1], lv.u[1]);
            *(u16x4*)(xh + dk0) = hv.v;
            *(u16x4*)(xl + dk0) = lv.v;
        }
}

// ---------------------------------------------------------------------------
extern "C" void kernel_launch(void* const* d_in, const int* in_sizes, int n_in,
                              void* d_out, int out_size, void* d_ws, size_t ws_size,
                              hipStream_t stream)
{
    const float* query = (const float*)d_in[0];
    const float* key   = (const float*)d_in[1];
    const float* value = (const float*)d_in[2];
    const float* Wq = (const float*)d_in[3];  const float* bq = (const float*)d_in[4];
    const float* Wk = (const float*)d_in[5];  const float* bk = (const float*)d_in[6];
    const float* Wv = (const float*)d_in[7];  const float* bv = (const float*)d_in[8];
    const float* Wo = (const float*)d_in[9];  const float* bo = (const float*)d_in[10];
    float* out = (float*)d_out;

    char* ws = (char*)d_ws;
    const size_t MB = (size_t)1 << 20;
    unsigned short* Xh  = (unsigned short*)(ws + 0*MB);
    unsigned short* Xl  = (unsigned short*)(ws + 8*MB);
    unsigned short* qb  = (unsigned short*)(ws + 16*MB);
    unsigned short* vt  = (unsigned short*)(ws + 24*MB);
    unsigned short* kb  = (unsigned short*)(ws + 40*MB);
    unsigned short* wsp = (unsigned short*)(ws + 48*MB);
    unsigned short* Woh = wsp + 3145728;     // Wo fp16

    wsplit4<<<2048, 256, 0, stream>>>(Wq, Wk, Wv, Wo, wsp);

    trigemm<<<dim3(32, 8, 3), 512, 0, stream>>>(query, key, value, wsp,
                                                bq, bk, bv, qb, kb, vt);

    attn_mfma8<<<256, 512, 0, stream>>>(qb, kb, vt, Xh, Xl);

    mfma_gemm0<<<dim3(32, 8), 512, 0, stream>>>(Xh, Xl, Woh, bo, out);
}

// Round 24
// 122.452 us; speedup vs baseline: 1.0106x; 1.0106x over previous
//
#include <hip/hip_runtime.h>
#include <hip/hip_bf16.h>
#include <math.h>

// B=2, S=2048, D=1024, H=16, dk=64.
// wsplit4 (W->fp16) -> tri-GEMM (r20 best: A fp32 reg-staged dist-1 -> fp16 LDS,
// 1-term fp16 MFMA, counted-vmcnt two-barrier) -> S-SPLIT attention (grid 512,
// 2 blocks/CU; raw partial O fp32 + l per half; additive since no max-shift)
// -> combine (X=(O0+O1)/(l0+l1) -> fp16 Xh) -> 1-term fp16 GEMM0.
//
// ws (64 MB): [0,16) P0 fp32 | [16,24) qb | [24,32) vt | [32,32.5) lbuf |
//  [40,48) kb -> Xh fp16 (combine-time reuse) | [48,56) W fp16 (Wq,Wk,Wv,Wo @2MB).
// P1 = d_out (scratch until gemm0 overwrites).
// Tiled K per (b,h): tile t at t*4096; elem(key r, dk d) = chunk(d>>3)*512+r*8+(d&7).
// Tiled V per (b,h): tile t at t*4096; elem(dk d, key s) = chunk((s&63)>>3)*512+d*8+(s&7).

#define B_ 2
#define S_ 2048
#define D_ 1024
#define H_ 16
#define DK 64

typedef __attribute__((ext_vector_type(8)))  __bf16    bf16x8;
typedef __attribute__((ext_vector_type(8)))  _Float16  f16x8;
typedef __attribute__((ext_vector_type(4)))  float     f32x4;
typedef __attribute__((ext_vector_type(16))) float     f32x16;
typedef __attribute__((ext_vector_type(8)))  unsigned short u16x8;
typedef __attribute__((ext_vector_type(4)))  unsigned short u16x4;

#if __has_builtin(__builtin_amdgcn_exp2f)
#define EXP2(x) __builtin_amdgcn_exp2f(x)
#else
#define EXP2(x) exp2f(x)
#endif

static __device__ __forceinline__ unsigned short f2bf(float x) {
    union { float f; unsigned u; } v; v.f = x;
    unsigned r = v.u + 0x7FFFu + ((v.u >> 16) & 1u);   // RNE
    return (unsigned short)(r >> 16);
}
static __device__ __forceinline__ unsigned cvtpk(float lo, float hi) {
    unsigned r;
    asm("v_cvt_pk_bf16_f32 %0, %1, %2" : "=v"(r) : "v"(lo), "v"(hi));
    return r;
}
static __device__ __forceinline__ unsigned cvtpk16(float lo, float hi) {
    unsigned r;
    asm("v_cvt_pkrtz_f16_f32 %0, %1, %2" : "=v"(r) : "v"(lo), "v"(hi));
    return r;
}
static __device__ __forceinline__ void gload_lds16(const void* g, void* l) {
    __builtin_amdgcn_global_load_lds(
        (const __attribute__((address_space(1))) void*)g,
        (__attribute__((address_space(3))) void*)l, 16, 0, 0);
}
static __device__ __forceinline__ int swz(int R, int c) {
    return ((R >> 1) << 6) + (((((R & 1) << 2) | c) ^ ((R >> 1) & 7)) << 3);
}

// ---------------------------------------------------------------------------
// All 4 weights fp32 -> fp16 (RNE). out: weight t at t*1M shorts ([48,56) MB).
// ---------------------------------------------------------------------------
__global__ __launch_bounds__(256) void wsplit4(
    const float* __restrict__ W0, const float* __restrict__ W1,
    const float* __restrict__ W2, const float* __restrict__ W3,
    unsigned short* __restrict__ out)
{
    const int idx = blockIdx.x * 256 + threadIdx.x;
    const int t = idx >> 17;
    const size_t e = (size_t)(idx & 131071) * 8;
    const float* src = (t==0 ? W0 : t==1 ? W1 : t==2 ? W2 : W3) + e;
    float4 a = *(const float4*)src;
    float4 b = *(const float4*)(src + 4);
    float x[8] = {a.x,a.y,a.z,a.w,b.x,b.y,b.z,b.w};
    union { _Float16 h[8]; u16x8 v; } Hh;
    #pragma unroll
    for (int j = 0; j < 8; ++j) Hh.h[j] = (_Float16)x[j];   // RNE
    *(u16x8*)(out + (size_t)t * 1048576 + e) = Hh.v;
}

// ---------------------------------------------------------------------------
// Fused tri-GEMM (r20/r22 exact): 1-term fp16 MFMA, A reg-staged dist-1.
// ---------------------------------------------------------------------------
__global__ __launch_bounds__(512) void trigemm(
    const float* __restrict__ Aq, const float* __restrict__ Ak,
    const float* __restrict__ Av, const unsigned short* __restrict__ wsp,
    const float* __restrict__ bq, const float* __restrict__ bk,
    const float* __restrict__ bv,
    unsigned short* __restrict__ qb, unsigned short* __restrict__ kb,
    unsigned short* __restrict__ vt)
{
    __shared__ __align__(16) char ldsb[32768];   // 2 bufs x (A16 8K | W 8K)
    const int pid = blockIdx.z;
    const float* A    = (pid==0) ? Aq : (pid==1) ? Ak : Av;
    const float* bias = (pid==0) ? bq : (pid==1) ? bk : bv;
    const unsigned short* Whp = wsp + (size_t)pid * 1048576;

    const int tid = threadIdx.x;
    const int w = tid >> 6, lane = tid & 63;
    const int l15 = lane & 15, g4 = lane >> 4;
    const int wr = w >> 1, wc = w & 1;
    const int bx = blockIdx.x, by = blockIdx.y;

    const int arow = tid >> 2, ac = tid & 3;
    const float* gpA = A + (size_t)(bx*128 + arow) * 1024 + ac * 8;
    const int aoff = swz(arow, ac);

    const int sr_ = tid >> 3, slot_ = tid & 7;
    const int z_  = slot_ ^ (sr_ & 7);
    const int wR_ = sr_*2 + (z_ >> 2);
    const unsigned short* gpW = Whp + (size_t)(by*128 + wR_) * 1024 + (z_ & 3) * 8;

    f32x4 acc[2][4];
    #pragma unroll
    for (int m = 0; m < 2; ++m)
        #pragma unroll
        for (int n = 0; n < 4; ++n) acc[m][n] = (f32x4){0.f,0.f,0.f,0.f};

    {
        float4 p0 = *(const float4*)(gpA);
        float4 p1 = *(const float4*)(gpA + 4);
        gload_lds16(gpW, ldsb + 8192 + tid * 16);
        union { unsigned u[4]; u16x8 v; } hh;
        hh.u[0] = cvtpk16(p0.x, p0.y); hh.u[1] = cvtpk16(p0.z, p0.w);
        hh.u[2] = cvtpk16(p1.x, p1.y); hh.u[3] = cvtpk16(p1.z, p1.w);
        *(u16x8*)((unsigned short*)ldsb + aoff) = hh.v;
    }
    asm volatile("s_waitcnt vmcnt(0) lgkmcnt(0)" ::: "memory");
    __builtin_amdgcn_s_barrier();
    asm volatile("" ::: "memory");

    for (int t = 0; t < 32; ++t) {
        const int cur = t & 1;
        float4 n0, n1;
        if (t < 31) {
            n0 = *(const float4*)(gpA + (t+1)*32);
            n1 = *(const float4*)(gpA + (t+1)*32 + 4);
            gload_lds16(gpW + (size_t)(t+1)*32, ldsb + (cur^1)*16384 + 8192 + tid*16);
            asm volatile("s_waitcnt vmcnt(3)" ::: "memory");
        } else {
            asm volatile("s_waitcnt vmcnt(0)" ::: "memory");
        }
        __builtin_amdgcn_s_barrier();
        asm volatile("" ::: "memory");

        const unsigned short* Ab = (const unsigned short*)(ldsb + cur*16384);
        const unsigned short* Wb = Ab + 4096;
        f16x8 ah[2], wh4[4];
        #pragma unroll
        for (int m = 0; m < 2; ++m)
            ah[m] = *(const f16x8*)(Ab + swz(wr*32 + m*16 + l15, g4));
        #pragma unroll
        for (int n = 0; n < 4; ++n)
            wh4[n] = *(const f16x8*)(Wb + swz(wc*64 + n*16 + l15, g4));
        #pragma unroll
        for (int m = 0; m < 2; ++m)
            #pragma unroll
            for (int n = 0; n < 4; ++n)
                acc[m][n] = __builtin_amdgcn_mfma_f32_16x16x32_f16(ah[m], wh4[n], acc[m][n], 0,0,0);

        if (t < 31) {
            union { unsigned u[4]; u16x8 v; } hh;
            hh.u[0] = cvtpk16(n0.x, n0.y); hh.u[1] = cvtpk16(n0.z, n0.w);
            hh.u[2] = cvtpk16(n1.x, n1.y); hh.u[3] = cvtpk16(n1.z, n1.w);
            *(u16x8*)((unsigned short*)(ldsb + (cur^1)*16384) + aoff) = hh.v;
        }
        asm volatile("s_waitcnt lgkmcnt(0)" ::: "memory");
        __builtin_amdgcn_s_barrier();
        asm volatile("" ::: "memory");
    }

    const int colBase = by*128 + wc*64;
    const int rowBase = bx*128 + wr*32;
    const int h = colBase >> 6;

    if (pid < 2) {
        unsigned short* Out = pid ? kb : qb;
        const float QSC = pid ? 1.0f : 0.125f * 1.44269504088896340736f;
        #pragma unroll
        for (int m = 0; m < 2; ++m) {
            const int srow0 = rowBase + m*16 + g4*4;
            const int b = srow0 >> 11;
            unsigned short* hb2 = Out + (size_t)(b*H_ + h) * S_ * DK;
            #pragma unroll
            for (int n = 0; n < 2; ++n) {
                const int d = n*16 + l15;
                const float invf = exp2f((float)d * -0.4152410118609203f);
                const float b1 = bias[h*64 + d], b2 = bias[h*64 + d + 32];
                #pragma unroll
                for (int r = 0; r < 4; ++r) {
                    const int s = (srow0 + r) & 2047;
                    const float x1 = acc[m][n][r]   + b1;
                    const float x2 = acc[m][n+2][r] + b2;
                    float sn, cc;
                    __sincosf((float)s * invf, &sn, &cc);
                    const float o1 = (x1*cc - x2*sn) * QSC;
                    const float o2 = (x2*cc + x1*sn) * QSC;
                    if (pid == 0) {
                        unsigned short* dst = hb2 + (size_t)s * DK;
                        dst[d]      = f2bf(o1);
                        dst[d + 32] = f2bf(o2);
                    } else {
                        unsigned short* tb = hb2 + (s >> 6) * 4096 + (s & 63) * 8;
                        tb[(d >> 3) * 512 + (d & 7)]        = f2bf(o1);
                        tb[(d >> 3) * 512 + 2048 + (d & 7)] = f2bf(o2);
                    }
                }
            }
        }
    } else {
        #pragma unroll
        for (int m = 0; m < 2; ++m) {
            const int srow0 = rowBase + m*16 + g4*4;
            const int b = srow0 >> 11, s0 = srow0 & 2047;
            unsigned short* tb = vt + (size_t)(b*H_ + h) * S_ * DK
                               + (s0 >> 6) * 4096 + ((s0 & 63) >> 3) * 512 + (s0 & 7);
            #pragma unroll
            for (int n = 0; n < 4; ++n) {
                const int d = n*16 + l15;
                const float bb = bias[h*64 + d];
                u16x4 pk;
                #pragma unroll
                for (int r = 0; r < 4; ++r) pk[r] = f2bf(acc[m][n][r] + bb);
                *(u16x4*)(tb + d * 8) = pk;
            }
        }
    }
}

// ---------------------------------------------------------------------------
// S-split flash attention. grid 512 = 32 bh x 8 qt x 2 halves (2 blocks/CU,
// 4 waves/SIMD). Each block: 8 key-tiles (half*8 .. +8); raw partial O (fp32)
// and l written to P[half]/lbuf — partial sums exactly additive (no max shift).
// ---------------------------------------------------------------------------
__global__ __launch_bounds__(512, 1) void attn_mfma9(
    const unsigned short* __restrict__ Qb, const unsigned short* __restrict__ Kb,
    const unsigned short* __restrict__ Vt,
    float* __restrict__ P0, float* __restrict__ P1, float* __restrict__ lbuf)
{
    __shared__ __align__(16) char lds[65536];
    const unsigned bid = blockIdx.x;             // 512 blocks
    const int xcd = bid & 7, idx = bid >> 3;     // idx 0..63
    const int bh   = xcd * 4 + (idx >> 4);       // 4 bh per XCD
    const int qt   = (idx >> 1) & 7;
    const int half = idx & 1;
    const int tid = threadIdx.x;
    const int w = tid >> 6, lane = tid & 63;
    const int l31 = lane & 31, hi = lane >> 5;
    const size_t bhO = (size_t)bh * S_ * DK;
    const int q0 = qt * 256 + w * 32;
    const int t0 = half * 8;                     // first global tile

    const int u0   = w * 4;
    const int isV  = u0 >> 4;
    const int u15  = u0 & 15;
    const int su0  = u15 >> 3;
    const unsigned short* sb = (isV ? Vt : Kb) + bhO;
    const int ch0 = u15 & 7;
    char* const dbase = lds;

    bf16x8 qf[4];
    #pragma unroll
    for (int ks = 0; ks < 4; ++ks)
        qf[ks] = *(const bf16x8*)(Qb + bhO + (size_t)(q0 + l31) * DK + ks*16 + hi*8);

    f32x16 oT[2];
    #pragma unroll
    for (int dh = 0; dh < 2; ++dh)
        #pragma unroll
        for (int r = 0; r < 16; ++r) oT[dh][r] = 0.f;
    float l_ = 0.f;

    #define ASTAGE(T, BUF) do {                                                     \
        const unsigned short* g_ = sb + (size_t)((T)*2 + su0) * 4096 + ch0 * 512    \
                                   + lane * 8;                                      \
        char* d_ = dbase + (BUF)*32768 + isV*16384 + su0*8192 + ch0*1024 + lane*16; \
        gload_lds16(g_,         d_);                                                \
        gload_lds16(g_ + 512,   d_ + 1024);                                         \
        gload_lds16(g_ + 1024,  d_ + 2048);                                         \
        gload_lds16(g_ + 1536,  d_ + 3072);                                         \
    } while (0)

    ASTAGE(t0, 0);
    asm volatile("s_waitcnt vmcnt(0)" ::: "memory");
    __builtin_amdgcn_s_barrier();
    asm volatile("" ::: "memory");

    for (int t = 0; t < 8; ++t) {
        const int cur = t & 1;
        if (t < 7) {
            ASTAGE(t0 + t + 1, cur ^ 1);
            asm volatile("s_waitcnt vmcnt(4)" ::: "memory");
        } else {
            asm volatile("s_waitcnt vmcnt(0)" ::: "memory");
        }
        __builtin_amdgcn_s_barrier();
        asm volatile("" ::: "memory");

        const char* Kl = lds + cur * 32768;
        const char* Vl = Kl + 16384;

        f32x16 s2[4];
        __builtin_amdgcn_s_setprio(1);
        #pragma unroll
        for (int kb2 = 0; kb2 < 4; ++kb2) {
            f32x16 a;
            #pragma unroll
            for (int r = 0; r < 16; ++r) a[r] = 0.f;
            const char* kbase = Kl + (kb2 >> 1) * 8192 + ((kb2 & 1) * 32 + l31) * 16;
            #pragma unroll
            for (int ks = 0; ks < 4; ++ks) {
                bf16x8 kf = *(const bf16x8*)(kbase + (ks*2 + hi) * 1024);
                a = __builtin_amdgcn_mfma_f32_32x32x16_bf16(kf, qf[ks], a, 0, 0, 0);
            }
            s2[kb2] = a;
        }
        __builtin_amdgcn_s_setprio(0);

        {
            float lsum = 0.f;
            #pragma unroll
            for (int kb2 = 0; kb2 < 4; ++kb2)
                #pragma unroll
                for (int r = 0; r < 16; ++r) {
                    const float p = EXP2(s2[kb2][r]);
                    s2[kb2][r] = p; lsum += p;
                }
            l_ += lsum;
        }

        #pragma unroll
        for (int ks2 = 0; ks2 < 8; ++ks2) {
            const int kb2 = ks2 >> 1;
            const int R0  = (ks2 & 1) * 8;
            unsigned a0 = cvtpk(s2[kb2][R0+0], s2[kb2][R0+1]);
            unsigned a1 = cvtpk(s2[kb2][R0+2], s2[kb2][R0+3]);
            unsigned b0 = cvtpk(s2[kb2][R0+4], s2[kb2][R0+5]);
            unsigned b1 = cvtpk(s2[kb2][R0+6], s2[kb2][R0+7]);
            asm("v_permlane32_swap_b32 %0, %1" : "+v"(a0), "+v"(b0));
            asm("v_permlane32_swap_b32 %0, %1" : "+v"(a1), "+v"(b1));
            union { unsigned u[4]; bf16x8 v; } pf;
            pf.u[0] = a0; pf.u[1] = a1; pf.u[2] = b0; pf.u[3] = b1;
            const char* vbase = Vl + (ks2 >> 2) * 8192 + (((ks2 & 3) * 2) + hi) * 1024;
            __builtin_amdgcn_s_setprio(1);
            #pragma unroll
            for (int dh = 0; dh < 2; ++dh) {
                bf16x8 vf = *(const bf16x8*)(vbase + (dh*32 + l31) * 16);
                oT[dh] = __builtin_amdgcn_mfma_f32_32x32x16_bf16(vf, pf.v, oT[dh], 0, 0, 0);
            }
            __builtin_amdgcn_s_setprio(0);
        }

        asm volatile("" ::: "memory");
        __builtin_amdgcn_s_barrier();
        asm volatile("" ::: "memory");
    }
    #undef ASTAGE

    // ---- epilogue: raw partial O + l (additive across halves) ----
    l_ += __shfl_xor(l_, 32, 64);
    const int b = bh >> 4, h = bh & 15;
    const int q = q0 + l31;
    float* P = half ? P1 : P0;
    float* op = P + ((((size_t)b * S_ + q) * H_ + h) * DK);
    if (hi == 0) lbuf[half * 65536 + (bh << 11) + q] = l_;
    #pragma unroll
    for (int dh = 0; dh < 2; ++dh)
        #pragma unroll
        for (int tt = 0; tt < 4; ++tt) {
            const int dk0 = dh*32 + tt*8 + hi*4;
            float4 st = { oT[dh][tt*4+0], oT[dh][tt*4+1],
                          oT[dh][tt*4+2], oT[dh][tt*4+3] };
            *(float4*)(op + dk0) = st;
        }
}

// ---------------------------------------------------------------------------
// Combine: X = (P0 + P1) / (l0 + l1) -> fp16 RNE Xh. 8 elems/thread.
// ---------------------------------------------------------------------------
__global__ __launch_bounds__(256) void combine(
    const float* __restrict__ P0, const float* __restrict__ P1,
    const float* __restrict__ lbuf, unsigned short* __restrict__ Xh)
{
    const int gid = blockIdx.x * 256 + threadIdx.x;      // 0..512K-1
    const size_t e = (size_t)gid * 8;
    const int h = (gid >> 3) & 15, s = (gid >> 7) & 2047, b = gid >> 18;
    const int qidx = ((b * 16 + h) << 11) | s;
    const float inv = 1.0f / (lbuf[qidx] + lbuf[65536 + qidx]);
    float4 a0 = *(const float4*)(P0 + e);
    float4 a1 = *(const float4*)(P0 + e + 4);
    float4 c0 = *(const float4*)(P1 + e);
    float4 c1 = *(const float4*)(P1 + e + 4);
    float x[8] = { (a0.x+c0.x)*inv, (a0.y+c0.y)*inv, (a0.z+c0.z)*inv, (a0.w+c0.w)*inv,
                   (a1.x+c1.x)*inv, (a1.y+c1.y)*inv, (a1.z+c1.z)*inv, (a1.w+c1.w)*inv };
    union { _Float16 hh[8]; u16x8 v; } o;
    #pragma unroll
    for (int j = 0; j < 8; ++j) o.hh[j] = (_Float16)x[j];   // RNE
    *(u16x8*)(Xh + e) = o.v;
}

// ---------------------------------------------------------------------------
// Output projection: 1-term fp16 GEMM (Xh * Wo), counted-vmcnt two-barrier.
// ---------------------------------------------------------------------------
__global__ __launch_bounds__(512) void mfma_gemm0(
    const unsigned short* __restrict__ Ah, const unsigned short* __restrict__ Wh,
    const float* __restrict__ bias, float* __restrict__ Out)
{
    __shared__ __align__(16) char ldsb[32768];   // 2 bufs x (Xh 8K | W 8K)
    const int tid = threadIdx.x;
    const int w = tid >> 6, lane = tid & 63;
    const int l15 = lane & 15, g4 = lane >> 4;
    const int wr = w >> 1, wc = w & 1;
    const int bx = blockIdx.x, by = blockIdx.y;

    // staging roles: waves 0-3 -> tensor ten (0=Xh,1=W), half qq
    const int ten = (w >> 1) & 1, qq = w & 1;
    const unsigned short* gsrc = ten ? Wh : Ah;
    const int row0 = ten ? by * 128 : bx * 128;
    const int lr8 = lane >> 3;
    const int zz  = (lane & 7) ^ lr8;
    const int wR0 = qq*64 + (lr8 << 1) + (zz >> 2);
    const unsigned short* gp0 = gsrc + (size_t)(row0 + wR0) * 1024 + (zz & 3) * 8;

    f32x4 acc[2][4];
    #pragma unroll
    for (int m = 0; m < 2; ++m)
        #pragma unroll
        for (int n = 0; n < 4; ++n) acc[m][n] = (f32x4){0.f,0.f,0.f,0.f};

    #define STAGE(T, BUF) do {                                              \
        if (w < 4) {                                                        \
            const unsigned short* g_ = gp0 + (size_t)(T) * 32;              \
            char* d_ = ldsb + (BUF)*16384 + ten*8192 + qq*4096;             \
            gload_lds16(g_,          d_);                                   \
            gload_lds16(g_ + 16384,  d_ + 1024);                            \
            gload_lds16(g_ + 32768,  d_ + 2048);                            \
            gload_lds16(g_ + 49152,  d_ + 3072);                            \
        }                                                                   \
    } while (0)

    STAGE(0, 0);
    asm volatile("s_waitcnt vmcnt(0)" ::: "memory");
    __builtin_amdgcn_s_barrier();
    asm volatile("" ::: "memory");

    for (int t = 0; t < 32; ++t) {
        const int cur = t & 1;
        if (t < 31) {
            STAGE(t + 1, cur ^ 1);
            asm volatile("s_waitcnt vmcnt(4)" ::: "memory");
        } else {
            asm volatile("s_waitcnt vmcnt(0)" ::: "memory");
        }
        __builtin_amdgcn_s_barrier();
        asm volatile("" ::: "memory");

        const unsigned short* Ahb = (const unsigned short*)(ldsb + cur*16384);
        const unsigned short* Whb = Ahb + 4096;
        f16x8 ah2[2], wh4[4];
        #pragma unroll
        for (int m = 0; m < 2; ++m)
            ah2[m] = *(const f16x8*)(Ahb + swz(wr*32 + m*16 + l15, g4));
        #pragma unroll
        for (int n = 0; n < 4; ++n)
            wh4[n] = *(const f16x8*)(Whb + swz(wc*64 + n*16 + l15, g4));
        #pragma unroll
        for (int m = 0; m < 2; ++m)
            #pragma unroll
            for (int n = 0; n < 4; ++n)
                acc[m][n] = __builtin_amdgcn_mfma_f32_16x16x32_f16(ah2[m], wh4[n], acc[m][n], 0,0,0);

        asm volatile("" ::: "memory");
        __builtin_amdgcn_s_barrier();
        asm volatile("" ::: "memory");
    }
    #undef STAGE

    const int colBase = by*128 + wc*64;
    const int rowBase = bx*128 + wr*32;
    #pragma unroll
    for (int m = 0; m < 2; ++m) {
        const int row = rowBase + m*16 + g4*4;
        #pragma unroll
        for (int n = 0; n < 4; ++n) {
            const int col = colBase + n*16 + l15;
            const float bb = bias[col];
            #pragma unroll
            for (int r = 0; r < 4; ++r)
                Out[(size_t)(row + r) * 1024 + col] = acc[m][n][r] + bb;
        }
    }
}

// ---------------------------------------------------------------------------
extern "C" void kernel_launch(void* const* d_in, const int* in_sizes, int n_in,
                              void* d_out, int out_size, void* d_ws, size_t ws_size,
                              hipStream_t stream)
{
    const float* query = (const float*)d_in[0];
    const float* key   = (const float*)d_in[1];
    const float* value = (const float*)d_in[2];
    const float* Wq = (const float*)d_in[3];  const float* bq = (const float*)d_in[4];
    const float* Wk = (const float*)d_in[5];  const float* bk = (const float*)d_in[6];
    const float* Wv = (const float*)d_in[7];  const float* bv = (const float*)d_in[8];
    const float* Wo = (const float*)d_in[9];  const float* bo = (const float*)d_in[10];
    float* out = (float*)d_out;

    char* ws = (char*)d_ws;
    const size_t MB = (size_t)1 << 20;
    float*          P0   = (float*)(ws + 0*MB);            // 16 MB
    unsigned short* qb   = (unsigned short*)(ws + 16*MB);  // 8 MB
    unsigned short* vt   = (unsigned short*)(ws + 24*MB);  // 8 MB
    float*          lbuf = (float*)(ws + 32*MB);           // 512 KB
    unsigned short* kb   = (unsigned short*)(ws + 40*MB);  // 8 MB (attn)
    unsigned short* XhF  = (unsigned short*)(ws + 40*MB);  // 8 MB (combine+, kb dead)
    unsigned short* wsp  = (unsigned short*)(ws + 48*MB);  // 8 MB W fp16
    unsigned short* Woh  = wsp + 3145728;                  // Wo fp16 @ [54,56)
    float*          P1   = out;                            // d_out as scratch

    wsplit4<<<2048, 256, 0, stream>>>(Wq, Wk, Wv, Wo, wsp);

    trigemm<<<dim3(32, 8, 3), 512, 0, stream>>>(query, key, value, wsp,
                                                bq, bk, bv, qb, kb, vt);

    attn_mfma9<<<512, 512, 0, stream>>>(qb, kb, vt, P0, P1, lbuf);

    combine<<<2048, 256, 0, stream>>>(P0, P1, lbuf, XhF);

    mfma_gemm0<<<dim3(32, 8), 512, 0, stream>>>(XhF, Woh, bo, out);
}

// Round 25
// 108.352 us; speedup vs baseline: 1.1421x; 1.1301x over previous
//
#include <hip/hip_runtime.h>
#include <hip/hip_bf16.h>
#include <math.h>

// B=2, S=2048, D=1024, H=16, dk=64.
// wsplit4 (all W -> fp16) -> fused tri-GEMM (r20/r22 best: A fp32 reg-staged
// dist-1 -> fp16 LDS, 1-term fp16 MFMA, counted-vmcnt two-barrier, 32KB LDS)
// -> 32x32-MFMA flash attention (r22 structure; epilogue writes X as fp16 RNE
// single tensor) -> 1-term fp16 GEMM0 (X * Wo, r24-proven numerics).
//
// ws (64 MB): [0,8) Xh fp16 | [16,24) qb | [24,32) vt | [40,48) kb |
//  [48,56) W fp16: Wq @0, Wk @1M, Wv @2M, Wo @3M shorts.
// Tiled K per (b,h): tile t at t*4096; elem(key r, dk d) = chunk(d>>3)*512+r*8+(d&7).
// Tiled V per (b,h): tile t at t*4096; elem(dk d, key s) = chunk((s&63)>>3)*512+d*8+(s&7).

#define B_ 2
#define S_ 2048
#define D_ 1024
#define H_ 16
#define DK 64

typedef __attribute__((ext_vector_type(8)))  __bf16    bf16x8;
typedef __attribute__((ext_vector_type(8)))  _Float16  f16x8;
typedef __attribute__((ext_vector_type(4)))  float     f32x4;
typedef __attribute__((ext_vector_type(16))) float     f32x16;
typedef __attribute__((ext_vector_type(8)))  unsigned short u16x8;
typedef __attribute__((ext_vector_type(4)))  unsigned short u16x4;

#if __has_builtin(__builtin_amdgcn_exp2f)
#define EXP2(x) __builtin_amdgcn_exp2f(x)
#else
#define EXP2(x) exp2f(x)
#endif

static __device__ __forceinline__ unsigned short f2bf(float x) {
    union { float f; unsigned u; } v; v.f = x;
    unsigned r = v.u + 0x7FFFu + ((v.u >> 16) & 1u);   // RNE
    return (unsigned short)(r >> 16);
}
static __device__ __forceinline__ unsigned cvtpk(float lo, float hi) {
    unsigned r;
    asm("v_cvt_pk_bf16_f32 %0, %1, %2" : "=v"(r) : "v"(lo), "v"(hi));
    return r;
}
static __device__ __forceinline__ unsigned cvtpk16(float lo, float hi) {
    unsigned r;
    asm("v_cvt_pkrtz_f16_f32 %0, %1, %2" : "=v"(r) : "v"(lo), "v"(hi));
    return r;
}
static __device__ __forceinline__ void gload_lds16(const void* g, void* l) {
    __builtin_amdgcn_global_load_lds(
        (const __attribute__((address_space(1))) void*)g,
        (__attribute__((address_space(3))) void*)l, 16, 0, 0);
}
static __device__ __forceinline__ int swz(int R, int c) {
    return ((R >> 1) << 6) + (((((R & 1) << 2) | c) ^ ((R >> 1) & 7)) << 3);
}

// ---------------------------------------------------------------------------
// All 4 weights fp32 -> fp16 (RNE). out: weight t at t*1M shorts.
// ---------------------------------------------------------------------------
__global__ __launch_bounds__(256) void wsplit4(
    const float* __restrict__ W0, const float* __restrict__ W1,
    const float* __restrict__ W2, const float* __restrict__ W3,
    unsigned short* __restrict__ out)
{
    const int idx = blockIdx.x * 256 + threadIdx.x;
    const int t = idx >> 17;
    const size_t e = (size_t)(idx & 131071) * 8;
    const float* src = (t==0 ? W0 : t==1 ? W1 : t==2 ? W2 : W3) + e;
    float4 a = *(const float4*)src;
    float4 b = *(const float4*)(src + 4);
    float x[8] = {a.x,a.y,a.z,a.w,b.x,b.y,b.z,b.w};
    union { _Float16 h[8]; u16x8 v; } Hh;
    #pragma unroll
    for (int j = 0; j < 8; ++j) Hh.h[j] = (_Float16)x[j];   // RNE
    *(u16x8*)(out + (size_t)t * 1048576 + e) = Hh.v;
}

// ---------------------------------------------------------------------------
// Fused tri-GEMM (r20/r22 exact): 1-term fp16 MFMA, A reg-staged dist-1.
// ---------------------------------------------------------------------------
__global__ __launch_bounds__(512) void trigemm(
    const float* __restrict__ Aq, const float* __restrict__ Ak,
    const float* __restrict__ Av, const unsigned short* __restrict__ wsp,
    const float* __restrict__ bq, const float* __restrict__ bk,
    const float* __restrict__ bv,
    unsigned short* __restrict__ qb, unsigned short* __restrict__ kb,
    unsigned short* __restrict__ vt)
{
    __shared__ __align__(16) char ldsb[32768];   // 2 bufs x (A16 8K | W 8K)
    const int pid = blockIdx.z;
    const float* A    = (pid==0) ? Aq : (pid==1) ? Ak : Av;
    const float* bias = (pid==0) ? bq : (pid==1) ? bk : bv;
    const unsigned short* Whp = wsp + (size_t)pid * 1048576;

    const int tid = threadIdx.x;
    const int w = tid >> 6, lane = tid & 63;
    const int l15 = lane & 15, g4 = lane >> 4;
    const int wr = w >> 1, wc = w & 1;
    const int bx = blockIdx.x, by = blockIdx.y;

    const int arow = tid >> 2, ac = tid & 3;
    const float* gpA = A + (size_t)(bx*128 + arow) * 1024 + ac * 8;
    const int aoff = swz(arow, ac);

    const int sr_ = tid >> 3, slot_ = tid & 7;
    const int z_  = slot_ ^ (sr_ & 7);
    const int wR_ = sr_*2 + (z_ >> 2);
    const unsigned short* gpW = Whp + (size_t)(by*128 + wR_) * 1024 + (z_ & 3) * 8;

    f32x4 acc[2][4];
    #pragma unroll
    for (int m = 0; m < 2; ++m)
        #pragma unroll
        for (int n = 0; n < 4; ++n) acc[m][n] = (f32x4){0.f,0.f,0.f,0.f};

    {
        float4 p0 = *(const float4*)(gpA);
        float4 p1 = *(const float4*)(gpA + 4);
        gload_lds16(gpW, ldsb + 8192 + tid * 16);
        union { unsigned u[4]; u16x8 v; } hh;
        hh.u[0] = cvtpk16(p0.x, p0.y); hh.u[1] = cvtpk16(p0.z, p0.w);
        hh.u[2] = cvtpk16(p1.x, p1.y); hh.u[3] = cvtpk16(p1.z, p1.w);
        *(u16x8*)((unsigned short*)ldsb + aoff) = hh.v;
    }
    asm volatile("s_waitcnt vmcnt(0) lgkmcnt(0)" ::: "memory");
    __builtin_amdgcn_s_barrier();
    asm volatile("" ::: "memory");

    for (int t = 0; t < 32; ++t) {
        const int cur = t & 1;
        float4 n0, n1;
        if (t < 31) {
            n0 = *(const float4*)(gpA + (t+1)*32);
            n1 = *(const float4*)(gpA + (t+1)*32 + 4);
            gload_lds16(gpW + (size_t)(t+1)*32, ldsb + (cur^1)*16384 + 8192 + tid*16);
            asm volatile("s_waitcnt vmcnt(3)" ::: "memory");
        } else {
            asm volatile("s_waitcnt vmcnt(0)" ::: "memory");
        }
        __builtin_amdgcn_s_barrier();
        asm volatile("" ::: "memory");

        const unsigned short* Ab = (const unsigned short*)(ldsb + cur*16384);
        const unsigned short* Wb = Ab + 4096;
        f16x8 ah[2], wh4[4];
        #pragma unroll
        for (int m = 0; m < 2; ++m)
            ah[m] = *(const f16x8*)(Ab + swz(wr*32 + m*16 + l15, g4));
        #pragma unroll
        for (int n = 0; n < 4; ++n)
            wh4[n] = *(const f16x8*)(Wb + swz(wc*64 + n*16 + l15, g4));
        #pragma unroll
        for (int m = 0; m < 2; ++m)
            #pragma unroll
            for (int n = 0; n < 4; ++n)
                acc[m][n] = __builtin_amdgcn_mfma_f32_16x16x32_f16(ah[m], wh4[n], acc[m][n], 0,0,0);

        if (t < 31) {
            union { unsigned u[4]; u16x8 v; } hh;
            hh.u[0] = cvtpk16(n0.x, n0.y); hh.u[1] = cvtpk16(n0.z, n0.w);
            hh.u[2] = cvtpk16(n1.x, n1.y); hh.u[3] = cvtpk16(n1.z, n1.w);
            *(u16x8*)((unsigned short*)(ldsb + (cur^1)*16384) + aoff) = hh.v;
        }
        asm volatile("s_waitcnt lgkmcnt(0)" ::: "memory");
        __builtin_amdgcn_s_barrier();
        asm volatile("" ::: "memory");
    }

    const int colBase = by*128 + wc*64;
    const int rowBase = bx*128 + wr*32;
    const int h = colBase >> 6;

    if (pid < 2) {
        unsigned short* Out = pid ? kb : qb;
        const float QSC = pid ? 1.0f : 0.125f * 1.44269504088896340736f;
        #pragma unroll
        for (int m = 0; m < 2; ++m) {
            const int srow0 = rowBase + m*16 + g4*4;
            const int b = srow0 >> 11;
            unsigned short* hb2 = Out + (size_t)(b*H_ + h) * S_ * DK;
            #pragma unroll
            for (int n = 0; n < 2; ++n) {
                const int d = n*16 + l15;
                const float invf = exp2f((float)d * -0.4152410118609203f);
                const float b1 = bias[h*64 + d], b2 = bias[h*64 + d + 32];
                #pragma unroll
                for (int r = 0; r < 4; ++r) {
                    const int s = (srow0 + r) & 2047;
                    const float x1 = acc[m][n][r]   + b1;
                    const float x2 = acc[m][n+2][r] + b2;
                    float sn, cc;
                    __sincosf((float)s * invf, &sn, &cc);
                    const float o1 = (x1*cc - x2*sn) * QSC;
                    const float o2 = (x2*cc + x1*sn) * QSC;
                    if (pid == 0) {
                        unsigned short* dst = hb2 + (size_t)s * DK;
                        dst[d]      = f2bf(o1);
                        dst[d + 32] = f2bf(o2);
                    } else {
                        unsigned short* tb = hb2 + (s >> 6) * 4096 + (s & 63) * 8;
                        tb[(d >> 3) * 512 + (d & 7)]        = f2bf(o1);
                        tb[(d >> 3) * 512 + 2048 + (d & 7)] = f2bf(o2);
                    }
                }
            }
        }
    } else {
        #pragma unroll
        for (int m = 0; m < 2; ++m) {
            const int srow0 = rowBase + m*16 + g4*4;
            const int b = srow0 >> 11, s0 = srow0 & 2047;
            unsigned short* tb = vt + (size_t)(b*H_ + h) * S_ * DK
                               + (s0 >> 6) * 4096 + ((s0 & 63) >> 3) * 512 + (s0 & 7);
            #pragma unroll
            for (int n = 0; n < 4; ++n) {
                const int d = n*16 + l15;
                const float bb = bias[h*64 + d];
                u16x4 pk;
                #pragma unroll
                for (int r = 0; r < 4; ++r) pk[r] = f2bf(acc[m][n][r] + bb);
                *(u16x4*)(tb + d * 8) = pk;
            }
        }
    }
}

// ---------------------------------------------------------------------------
// 32x32-MFMA flash attention (r22 structure), epilogue: X -> fp16 RNE (1 tensor).
// ---------------------------------------------------------------------------
__global__ __launch_bounds__(512, 1) void attn_mfma8(
    const unsigned short* __restrict__ Qb, const unsigned short* __restrict__ Kb,
    const unsigned short* __restrict__ Vt, unsigned short* __restrict__ Xh)
{
    __shared__ __align__(16) char lds[65536];
    const unsigned bid = blockIdx.x;
    const int xcd = bid & 7, idx = bid >> 3;
    const int bh  = xcd * 4 + (idx >> 3);
    const int qt  = idx & 7;
    const int tid = threadIdx.x;
    const int w = tid >> 6, lane = tid & 63;
    const int l31 = lane & 31, hi = lane >> 5;
    const size_t bhO = (size_t)bh * S_ * DK;
    const int q0 = qt * 256 + w * 32;

    const int u0   = w * 4;
    const int isV  = u0 >> 4;
    const int u15  = u0 & 15;
    const int su0  = u15 >> 3;
    const unsigned short* sb = (isV ? Vt : Kb) + bhO;
    const int ch0 = u15 & 7;
    char* const dbase = lds;

    bf16x8 qf[4];
    #pragma unroll
    for (int ks = 0; ks < 4; ++ks)
        qf[ks] = *(const bf16x8*)(Qb + bhO + (size_t)(q0 + l31) * DK + ks*16 + hi*8);

    f32x16 oT[2];
    #pragma unroll
    for (int dh = 0; dh < 2; ++dh)
        #pragma unroll
        for (int r = 0; r < 16; ++r) oT[dh][r] = 0.f;
    float l_ = 0.f;

    #define ASTAGE(T, BUF) do {                                                     \
        const unsigned short* g_ = sb + (size_t)((T)*2 + su0) * 4096 + ch0 * 512    \
                                   + lane * 8;                                      \
        char* d_ = dbase + (BUF)*32768 + isV*16384 + su0*8192 + ch0*1024 + lane*16; \
        gload_lds16(g_,         d_);                                                \
        gload_lds16(g_ + 512,   d_ + 1024);                                         \
        gload_lds16(g_ + 1024,  d_ + 2048);                                         \
        gload_lds16(g_ + 1536,  d_ + 3072);                                         \
    } while (0)

    ASTAGE(0, 0);
    asm volatile("s_waitcnt vmcnt(0)" ::: "memory");
    __builtin_amdgcn_s_barrier();
    asm volatile("" ::: "memory");

    for (int t = 0; t < 16; ++t) {
        const int cur = t & 1;
        if (t < 15) {
            ASTAGE(t + 1, cur ^ 1);
            asm volatile("s_waitcnt vmcnt(4)" ::: "memory");
        } else {
            asm volatile("s_waitcnt vmcnt(0)" ::: "memory");
        }
        __builtin_amdgcn_s_barrier();
        asm volatile("" ::: "memory");

        const char* Kl = lds + cur * 32768;
        const char* Vl = Kl + 16384;

        f32x16 s2[4];
        __builtin_amdgcn_s_setprio(1);
        #pragma unroll
        for (int kb2 = 0; kb2 < 4; ++kb2) {
            f32x16 a;
            #pragma unroll
            for (int r = 0; r < 16; ++r) a[r] = 0.f;
            const char* kbase = Kl + (kb2 >> 1) * 8192 + ((kb2 & 1) * 32 + l31) * 16;
            #pragma unroll
            for (int ks = 0; ks < 4; ++ks) {
                bf16x8 kf = *(const bf16x8*)(kbase + (ks*2 + hi) * 1024);
                a = __builtin_amdgcn_mfma_f32_32x32x16_bf16(kf, qf[ks], a, 0, 0, 0);
            }
            s2[kb2] = a;
        }
        __builtin_amdgcn_s_setprio(0);

        {
            float lsum = 0.f;
            #pragma unroll
            for (int kb2 = 0; kb2 < 4; ++kb2)
                #pragma unroll
                for (int r = 0; r < 16; ++r) {
                    const float p = EXP2(s2[kb2][r]);
                    s2[kb2][r] = p; lsum += p;
                }
            l_ += lsum;
        }

        #pragma unroll
        for (int ks2 = 0; ks2 < 8; ++ks2) {
            const int kb2 = ks2 >> 1;
            const int R0  = (ks2 & 1) * 8;
            unsigned a0 = cvtpk(s2[kb2][R0+0], s2[kb2][R0+1]);
            unsigned a1 = cvtpk(s2[kb2][R0+2], s2[kb2][R0+3]);
            unsigned b0 = cvtpk(s2[kb2][R0+4], s2[kb2][R0+5]);
            unsigned b1 = cvtpk(s2[kb2][R0+6], s2[kb2][R0+7]);
            asm("v_permlane32_swap_b32 %0, %1" : "+v"(a0), "+v"(b0));
            asm("v_permlane32_swap_b32 %0, %1" : "+v"(a1), "+v"(b1));
            union { unsigned u[4]; bf16x8 v; } pf;
            pf.u[0] = a0; pf.u[1] = a1; pf.u[2] = b0; pf.u[3] = b1;
            const char* vbase = Vl + (ks2 >> 2) * 8192 + (((ks2 & 3) * 2) + hi) * 1024;
            __builtin_amdgcn_s_setprio(1);
            #pragma unroll
            for (int dh = 0; dh < 2; ++dh) {
                bf16x8 vf = *(const bf16x8*)(vbase + (dh*32 + l31) * 16);
                oT[dh] = __builtin_amdgcn_mfma_f32_32x32x16_bf16(vf, pf.v, oT[dh], 0, 0, 0);
            }
            __builtin_amdgcn_s_setprio(0);
        }

        asm volatile("" ::: "memory");
        __builtin_amdgcn_s_barrier();
        asm volatile("" ::: "memory");
    }
    #undef ASTAGE

    l_ += __shfl_xor(l_, 32, 64);
    const float inv = 1.0f / l_;
    const int b = bh >> 4, h = bh & 15;
    const int q = q0 + l31;
    unsigned short* xh = Xh + (((size_t)b * S_ + q) * H_ + h) * DK;
    #pragma unroll
    for (int dh = 0; dh < 2; ++dh)
        #pragma unroll
        for (int tt = 0; tt < 4; ++tt) {
            const int dk0 = dh*32 + tt*8 + hi*4;
            union { _Float16 hh[4]; u16x4 v; } o;
            #pragma unroll
            for (int r = 0; r < 4; ++r)
                o.hh[r] = (_Float16)(oT[dh][tt*4 + r] * inv);   // RNE
            *(u16x4*)(xh + dk0) = o.v;
        }
}

// ---------------------------------------------------------------------------
// Output projection: 1-term fp16 GEMM (Xh * Wo), counted-vmcnt two-barrier.
// ---------------------------------------------------------------------------
__global__ __launch_bounds__(512) void mfma_gemm0(
    const unsigned short* __restrict__ Ah, const unsigned short* __restrict__ Wh,
    const float* __restrict__ bias, float* __restrict__ Out)
{
    __shared__ __align__(16) char ldsb[32768];   // 2 bufs x (Xh 8K | W 8K)
    const int tid = threadIdx.x;
    const int w = tid >> 6, lane = tid & 63;
    const int l15 = lane & 15, g4 = lane >> 4;
    const int wr = w >> 1, wc = w & 1;
    const int bx = blockIdx.x, by = blockIdx.y;

    // staging roles: waves 0-3 -> tensor ten (0=Xh,1=W), half qq
    const int ten = (w >> 1) & 1, qq = w & 1;
    const unsigned short* gsrc = ten ? Wh : Ah;
    const int row0 = ten ? by * 128 : bx * 128;
    const int lr8 = lane >> 3;
    const int zz  = (lane & 7) ^ lr8;
    const int wR0 = qq*64 + (lr8 << 1) + (zz >> 2);
    const unsigned short* gp0 = gsrc + (size_t)(row0 + wR0) * 1024 + (zz & 3) * 8;

    f32x4 acc[2][4];
    #pragma unroll
    for (int m = 0; m < 2; ++m)
        #pragma unroll
        for (int n = 0; n < 4; ++n) acc[m][n] = (f32x4){0.f,0.f,0.f,0.f};

    #define STAGE(T, BUF) do {                                              \
        if (w < 4) {                                                        \
            const unsigned short* g_ = gp0 + (size_t)(T) * 32;              \
            char* d_ = ldsb + (BUF)*16384 + ten*8192 + qq*4096;             \
            gload_lds16(g_,          d_);                                   \
            gload_lds16(g_ + 16384,  d_ + 1024);                            \
            gload_lds16(g_ + 32768,  d_ + 2048);                            \
            gload_lds16(g_ + 49152,  d_ + 3072);                            \
        }                                                                   \
    } while (0)

    STAGE(0, 0);
    asm volatile("s_waitcnt vmcnt(0)" ::: "memory");
    __builtin_amdgcn_s_barrier();
    asm volatile("" ::: "memory");

    for (int t = 0; t < 32; ++t) {
        const int cur = t & 1;
        if (t < 31) {
            STAGE(t + 1, cur ^ 1);
            asm volatile("s_waitcnt vmcnt(4)" ::: "memory");
        } else {
            asm volatile("s_waitcnt vmcnt(0)" ::: "memory");
        }
        __builtin_amdgcn_s_barrier();
        asm volatile("" ::: "memory");

        const unsigned short* Ahb = (const unsigned short*)(ldsb + cur*16384);
        const unsigned short* Whb = Ahb + 4096;
        f16x8 ah2[2], wh4[4];
        #pragma unroll
        for (int m = 0; m < 2; ++m)
            ah2[m] = *(const f16x8*)(Ahb + swz(wr*32 + m*16 + l15, g4));
        #pragma unroll
        for (int n = 0; n < 4; ++n)
            wh4[n] = *(const f16x8*)(Whb + swz(wc*64 + n*16 + l15, g4));
        #pragma unroll
        for (int m = 0; m < 2; ++m)
            #pragma unroll
            for (int n = 0; n < 4; ++n)
                acc[m][n] = __builtin_amdgcn_mfma_f32_16x16x32_f16(ah2[m], wh4[n], acc[m][n], 0,0,0);

        asm volatile("" ::: "memory");
        __builtin_amdgcn_s_barrier();
        asm volatile("" ::: "memory");
    }
    #undef STAGE

    const int colBase = by*128 + wc*64;
    const int rowBase = bx*128 + wr*32;
    #pragma unroll
    for (int m = 0; m < 2; ++m) {
        const int row = rowBase + m*16 + g4*4;
        #pragma unroll
        for (int n = 0; n < 4; ++n) {
            const int col = colBase + n*16 + l15;
            const float bb = bias[col];
            #pragma unroll
            for (int r = 0; r < 4; ++r)
                Out[(size_t)(row + r) * 1024 + col] = acc[m][n][r] + bb;
        }
    }
}

// ---------------------------------------------------------------------------
extern "C" void kernel_launch(void* const* d_in, const int* in_sizes, int n_in,
                              void* d_out, int out_size, void* d_ws, size_t ws_size,
                              hipStream_t stream)
{
    const float* query = (const float*)d_in[0];
    const float* key   = (const float*)d_in[1];
    const float* value = (const float*)d_in[2];
    const float* Wq = (const float*)d_in[3];  const float* bq = (const float*)d_in[4];
    const float* Wk = (const float*)d_in[5];  const float* bk = (const float*)d_in[6];
    const float* Wv = (const float*)d_in[7];  const float* bv = (const float*)d_in[8];
    const float* Wo = (const float*)d_in[9];  const float* bo = (const float*)d_in[10];
    float* out = (float*)d_out;

    char* ws = (char*)d_ws;
    const size_t MB = (size_t)1 << 20;
    unsigned short* Xh  = (unsigned short*)(ws + 0*MB);
    unsigned short* qb  = (unsigned short*)(ws + 16*MB);
    unsigned short* vt  = (unsigned short*)(ws + 24*MB);
    unsigned short* kb  = (unsigned short*)(ws + 40*MB);
    unsigned short* wsp = (unsigned short*)(ws + 48*MB);
    unsigned short* Woh = wsp + 3145728;     // Wo fp16

    wsplit4<<<2048, 256, 0, stream>>>(Wq, Wk, Wv, Wo, wsp);

    trigemm<<<dim3(32, 8, 3), 512, 0, stream>>>(query, key, value, wsp,
                                                bq, bk, bv, qb, kb, vt);

    attn_mfma8<<<256, 512, 0, stream>>>(qb, kb, vt, Xh);

    mfma_gemm0<<<dim3(32, 8), 512, 0, stream>>>(Xh, Woh, bo, out);
}